// Round 7
// baseline (146.108 us; speedup 1.0000x reference)
//
#include <hip/hip_runtime.h>
#include <hip/hip_bf16.h>

#define R_BINS 50
#define NFEAT 7
#define HSZ (R_BINS * NFEAT)   // 350
#define STW 536                // u16 per LDS row: 1072 B (16B-multiple, bank-skewed)

typedef __attribute__((ext_vector_type(8))) short short8;   // 8 bf16
typedef __attribute__((ext_vector_type(4))) float f32x4;
typedef unsigned short u16x2 __attribute__((ext_vector_type(2)));

__device__ __forceinline__ unsigned pksub(unsigned a, unsigned b) {
    u16x2 r = __builtin_bit_cast(u16x2, a) - __builtin_bit_cast(u16x2, b);
    return __builtin_bit_cast(unsigned, r);
}
__device__ __forceinline__ u16x2 pkmax(unsigned a, unsigned b) {
    return __builtin_elementwise_max(__builtin_bit_cast(u16x2, a),
                                     __builtin_bit_cast(u16x2, b));
}
// dcol_minus_tile -> packed one-hot (bf16 2.0 where halfword == 0)
__device__ __forceinline__ unsigned oh(unsigned d) {
    u16x2 dd = __builtin_bit_cast(u16x2, d);
    u16x2 one = {1, 1};
    u16x2 m = __builtin_elementwise_min(dd, one);   // 0 iff match else 1
    return ((__builtin_bit_cast(unsigned, m)) ^ 0x00010001u) << 14;  // 0x4000 = bf16 2.0
}

__global__ __launch_bounds__(256) void disk_hist_kernel(
    const float* __restrict__ pos,
    const float* __restrict__ vel,
    const float* __restrict__ mass,
    float* __restrict__ ghist,
    int n)
{
    // rows 0..6: bf16 features; row 7: zeros (B for cols 7..15); row 8: bins u16
    __shared__ unsigned short st16[9][STW];
    __shared__ float mg[4][HSZ];

    const int tid  = threadIdx.x;
    const int lane = tid & 63;
    const int w    = tid >> 6;
    const int col  = lane & 15;
    const int g    = lane >> 4;

    // zero row 7 once (each wave zeroes its own read range: element i by thread i%256)
    for (int i = tid; i < STW; i += 256) st16[7][i] = 0;
    __syncthreads();

    f32x4 acc[4] = {{0,0,0,0},{0,0,0,0},{0,0,0,0},{0,0,0,0}};

    // hoisted consumer pointers (constant per thread)
    const int brow = (col < NFEAT) ? col : 7;
    const unsigned short* pB0 = &st16[brow][(w << 6) + (g << 3)];
    const unsigned short* pB1 = pB0 + 32;
    const unsigned short* pN0 = &st16[8][(w << 6) + (g << 3)];
    const unsigned short* pN1 = pN0 + 32;
    const unsigned colpk = (unsigned)col * 0x00010001u;

    const int stride = gridDim.x * blockDim.x;
    const int gtid   = blockIdx.x * blockDim.x + tid;
    const int nquads = n >> 2;
    const int niter  = (nquads + stride - 1) / stride;

    const float4* pos4  = (const float4*)pos;
    const float4* vel4  = (const float4*)vel;
    const float4* mass4 = (const float4*)mass;

    for (int it = 0; it < niter; ++it) {
        int q = it * stride + gtid;
        bool valid = q < nquads;
        float px[4], py[4], vx[4], vy[4], vzc[4], mm[4];
        if (valid) {
            float4 p0 = pos4[3*q+0], p1 = pos4[3*q+1], p2 = pos4[3*q+2];
            float4 v0 = vel4[3*q+0], v1 = vel4[3*q+1], v2 = vel4[3*q+2];
            float4 m  = mass4[q];
            px[0]=p0.x; px[1]=p0.w; px[2]=p1.z; px[3]=p2.y;
            py[0]=p0.y; py[1]=p1.x; py[2]=p1.w; py[3]=p2.z;
            vx[0]=v0.x; vx[1]=v0.w; vx[2]=v1.z; vx[3]=v2.y;
            vy[0]=v0.y; vy[1]=v1.x; vy[2]=v1.w; vy[3]=v2.z;
            vzc[0]=v0.z; vzc[1]=v1.y; vzc[2]=v2.x; vzc[3]=v2.w;
            mm[0]=m.x;  mm[1]=m.y;  mm[2]=m.z;  mm[3]=m.w;
        } else {
            #pragma unroll
            for (int k2 = 0; k2 < 4; ++k2)
                px[k2]=py[k2]=vx[k2]=vy[k2]=vzc[k2]=mm[k2]=0.0f;
        }

        #pragma unroll
        for (int k = 0; k < 4; ++k) {
            // ---------- producer: this thread's particle ----------
            float x = px[k], y = py[k];
            float r = sqrtf(x*x + y*y);
            int   bi = (int)(r * 5.0f);                  // DR = 0.2, r >= 0
            bool  ok = valid && (r > 0.0f) && (bi < R_BINS);
            float invr = ok ? (1.0f / r) : 0.0f;
            float wg   = ok ? mm[k] : 0.0f;
            unsigned short bin16 = ok ? (unsigned short)bi : (unsigned short)0;
            float vr = (x*vx[k] + y*vy[k]) * invr;
            float vp = (y*vx[k] - x*vy[k]) * invr;
            float f0 = wg;
            float f1 = wg * vr,      f2 = f1 * vr;
            float f3 = wg * vp,      f4 = f3 * vp;
            float f5 = wg * vzc[k],  f6 = f5 * vzc[k];

            st16[0][tid] = __builtin_bit_cast(unsigned short, (__hip_bfloat16)f0);
            st16[1][tid] = __builtin_bit_cast(unsigned short, (__hip_bfloat16)f1);
            st16[2][tid] = __builtin_bit_cast(unsigned short, (__hip_bfloat16)f2);
            st16[3][tid] = __builtin_bit_cast(unsigned short, (__hip_bfloat16)f3);
            st16[4][tid] = __builtin_bit_cast(unsigned short, (__hip_bfloat16)f4);
            st16[5][tid] = __builtin_bit_cast(unsigned short, (__hip_bfloat16)f5);
            st16[6][tid] = __builtin_bit_cast(unsigned short, (__hip_bfloat16)f6);
            st16[8][tid] = bin16;
            // no barrier: staging is wave-local; same-wave LDS ops are ordered

            // ---------- consumer: 2 batches of 32 particles ----------
            #pragma unroll
            for (int b = 0; b < 2; ++b) {
                const unsigned short* pB = b ? pB1 : pB0;
                const unsigned short* pN = b ? pN1 : pN0;
                uint4 Braw = *(const uint4*)pB;      // 8 bf16 feats (row=col)
                uint4 Nraw = *(const uint4*)pN;      // 8 bins as u16 pairs
                short8 Bv = __builtin_bit_cast(short8, Braw);

                unsigned dc0 = pksub(Nraw.x, colpk);
                unsigned dc1 = pksub(Nraw.y, colpk);
                unsigned dc2 = pksub(Nraw.z, colpk);
                unsigned dc3 = pksub(Nraw.w, colpk);

                union { unsigned u[4]; short8 v; } A;

                // tile 0
                A.u[0]=oh(dc0); A.u[1]=oh(dc1); A.u[2]=oh(dc2); A.u[3]=oh(dc3);
                acc[0] = __builtin_amdgcn_mfma_f32_16x16x32_bf16(A.v, Bv, acc[0], 0,0,0);
                // tile 1
                A.u[0]=oh(pksub(dc0,0x00100010u)); A.u[1]=oh(pksub(dc1,0x00100010u));
                A.u[2]=oh(pksub(dc2,0x00100010u)); A.u[3]=oh(pksub(dc3,0x00100010u));
                acc[1] = __builtin_amdgcn_mfma_f32_16x16x32_bf16(A.v, Bv, acc[1], 0,0,0);
                // tile 2
                A.u[0]=oh(pksub(dc0,0x00200020u)); A.u[1]=oh(pksub(dc1,0x00200020u));
                A.u[2]=oh(pksub(dc2,0x00200020u)); A.u[3]=oh(pksub(dc3,0x00200020u));
                acc[2] = __builtin_amdgcn_mfma_f32_16x16x32_bf16(A.v, Bv, acc[2], 0,0,0);
                // tile 3: bins 48..63 are ~0.2% of particles -> usually skippable
                u16x2 mx = __builtin_elementwise_max(pkmax(Nraw.x, Nraw.y),
                                                     pkmax(Nraw.z, Nraw.w));
                unsigned mv = __builtin_bit_cast(unsigned, mx);
                unsigned ms = (mv & 0xFFFFu) > (mv >> 16) ? (mv & 0xFFFFu) : (mv >> 16);
                if (__any((int)(ms >= 48))) {
                    A.u[0]=oh(pksub(dc0,0x00300030u)); A.u[1]=oh(pksub(dc1,0x00300030u));
                    A.u[2]=oh(pksub(dc2,0x00300030u)); A.u[3]=oh(pksub(dc3,0x00300030u));
                    acc[3] = __builtin_amdgcn_mfma_f32_16x16x32_bf16(A.v, Bv, acc[3], 0,0,0);
                }
            }
        }
    }

    // ---- per-wave D tiles -> LDS (A used 2.0, so scale by 0.5) ----
    if (col < NFEAT) {
        #pragma unroll
        for (int t = 0; t < 4; ++t) {
            #pragma unroll
            for (int r = 0; r < 4; ++r) {
                int bin = 16*t + 4*g + r;    // D: col=lane&15, row=(lane>>4)*4+r
                if (bin < R_BINS)
                    mg[w][bin * NFEAT + col] = acc[t][r] * 0.5f;
            }
        }
    }
    __syncthreads();

    for (int i = tid; i < HSZ; i += blockDim.x) {
        float s = mg[0][i] + mg[1][i] + mg[2][i] + mg[3][i];
        atomicAdd(ghist + i, s);
    }

    // ---- exact scalar tail (n % 4), block 0 ----
    if (blockIdx.x == 0 && tid < (n & 3)) {
        int p = (nquads << 2) + tid;
        float x = pos[3*p], y = pos[3*p + 1];
        float r = sqrtf(x*x + y*y);
        int bin = (int)floorf(r * 5.0f);
        if (bin >= 0 && bin < R_BINS && r > 0.0f) {
            float invr = 1.0f / r;
            float vxs = vel[3*p], vys = vel[3*p+1], vzs = vel[3*p+2];
            float vr = (x*vxs + y*vys) * invr;
            float vp = (y*vxs - x*vys) * invr;
            float wg = mass[p];
            float* bptr = ghist + bin * NFEAT;
            atomicAdd(bptr + 0, wg);
            atomicAdd(bptr + 1, wg * vr);
            atomicAdd(bptr + 2, wg * vr * vr);
            atomicAdd(bptr + 3, wg * vp);
            atomicAdd(bptr + 4, wg * vp * vp);
            atomicAdd(bptr + 5, wg * vzs);
            atomicAdd(bptr + 6, wg * vzs * vzs);
        }
    }
}

__global__ void disk_finalize_kernel(const float* __restrict__ gh,
                                     float* __restrict__ out)
{
    int b = threadIdx.x;
    if (b >= R_BINS) return;
    const float* s = gh + b * NFEAT;
    float inv  = 1.0f / s[0];
    float vr_m = s[1] * inv, vr2 = s[2] * inv;
    float vp_m = s[3] * inv, vp2 = s[4] * inv;
    float vz_m = s[5] * inv, vz2 = s[6] * inv;
    out[0 * R_BINS + b] = vp_m;
    out[1 * R_BINS + b] = sqrtf(vp2 - vp_m * vp_m);
    out[2 * R_BINS + b] = vr_m;
    out[3 * R_BINS + b] = sqrtf(vr2 - vr_m * vr_m);
    out[4 * R_BINS + b] = vz_m;
    out[5 * R_BINS + b] = sqrtf(vz2 - vz_m * vz_m);
}

extern "C" void kernel_launch(void* const* d_in, const int* in_sizes, int n_in,
                              void* d_out, int out_size, void* d_ws, size_t ws_size,
                              hipStream_t stream)
{
    const float* pos  = (const float*)d_in[0];
    const float* vel  = (const float*)d_in[1];
    const float* mass = (const float*)d_in[2];
    float* out   = (float*)d_out;
    float* ghist = (float*)d_ws;
    int n = in_sizes[2];   // masses: one per particle

    hipMemsetAsync(ghist, 0, HSZ * sizeof(float), stream);

    disk_hist_kernel<<<2048, 256, 0, stream>>>(pos, vel, mass, ghist, n);
    disk_finalize_kernel<<<1, 64, 0, stream>>>(ghist, out);
}

// Round 8
// 145.706 us; speedup vs baseline: 1.0028x; 1.0028x over previous
//
#include <hip/hip_runtime.h>
#include <hip/hip_bf16.h>

#define R_BINS 50
#define NFEAT 7
#define HSZ (R_BINS * NFEAT)   // 350
#define STW 520                // u16 per LDS row: 1040B stride (rows hit distinct bank groups)

typedef __attribute__((ext_vector_type(8))) short short8;   // 8 bf16
typedef __attribute__((ext_vector_type(4))) float f32x4;
typedef unsigned short u16x2 __attribute__((ext_vector_type(2)));

__device__ __forceinline__ unsigned pksub(unsigned a, unsigned b) {
    u16x2 r = __builtin_bit_cast(u16x2, a) - __builtin_bit_cast(u16x2, b);
    return __builtin_bit_cast(unsigned, r);
}
__device__ __forceinline__ u16x2 pkmax(unsigned a, unsigned b) {
    return __builtin_elementwise_max(__builtin_bit_cast(u16x2, a),
                                     __builtin_bit_cast(u16x2, b));
}
// packed one-hot: bf16 2.0 where halfword == 0
__device__ __forceinline__ unsigned oh(unsigned d) {
    u16x2 dd = __builtin_bit_cast(u16x2, d);
    u16x2 one = {1, 1};
    u16x2 m = __builtin_elementwise_min(dd, one);   // 0 iff match else 1
    return ((__builtin_bit_cast(unsigned, m)) ^ 0x00010001u) << 14;  // 0x4000 = bf16 2.0
}

__device__ __forceinline__ unsigned short to_bf16u(float f) {
    return __builtin_bit_cast(unsigned short, (__hip_bfloat16)f);
}

__global__ __launch_bounds__(256, 4) void disk_hist_kernel(
    const float* __restrict__ pos,
    const float* __restrict__ vel,
    const float* __restrict__ mass,
    float* __restrict__ ghist,
    int n)
{
    // two staging buffers (ping-pong per k-step); rows 0..6 bf16 feats,
    // row 7 zeros (B rows for cols 7..15), row 8 bins u16
    __shared__ unsigned short st16[2][9][STW];
    __shared__ float mg[4][HSZ];

    const int tid  = threadIdx.x;
    const int lane = tid & 63;
    const int w    = tid >> 6;
    const int col  = lane & 15;
    const int g    = lane >> 4;

    for (int i = tid; i < STW; i += 256) { st16[0][7][i] = 0; st16[1][7][i] = 0; }
    __syncthreads();

    f32x4 acc[4] = {{0,0,0,0},{0,0,0,0},{0,0,0,0},{0,0,0,0}};

    const int brow = (col < NFEAT) ? col : 7;
    // per-(buffer,batch) LDS pointers, constant per thread
    const unsigned short* pB[2][2];
    const unsigned short* pN[2][2];
    {
        const int co = (w << 6) + (g << 3);
        pB[0][0] = &st16[0][brow][co];  pB[0][1] = pB[0][0] + 32;
        pB[1][0] = &st16[1][brow][co];  pB[1][1] = pB[1][0] + 32;
        pN[0][0] = &st16[0][8][co];     pN[0][1] = pN[0][0] + 32;
        pN[1][0] = &st16[1][8][co];     pN[1][1] = pN[1][0] + 32;
    }
    const unsigned colpk = (unsigned)col * 0x00010001u;

    const int stride = gridDim.x * blockDim.x;    // 393216
    const int gtid   = blockIdx.x * blockDim.x + tid;
    const int nquads = n >> 2;
    const int niter  = (nquads + stride - 1) / stride;

    const float4* pos4  = (const float4*)pos;
    const float4* vel4  = (const float4*)vel;
    const float4* mass4 = (const float4*)mass;

    // ---------- helpers ----------
    #define STAGE(U, X, Y, VX, VY, VZ, M, VALID) do {                          \
        float x_ = (X), y_ = (Y);                                              \
        float r_ = sqrtf(x_*x_ + y_*y_);                                       \
        int   bi_ = (int)(r_ * 5.0f);                                          \
        bool  ok_ = (VALID) && (r_ > 0.0f) && (bi_ < R_BINS);                  \
        float invr_ = ok_ ? (1.0f / r_) : 0.0f;                                \
        float wg_   = ok_ ? (M) : 0.0f;                                        \
        unsigned short b16_ = ok_ ? (unsigned short)bi_ : (unsigned short)0;   \
        float vr_ = (x_*(VX) + y_*(VY)) * invr_;                               \
        float vp_ = (y_*(VX) - x_*(VY)) * invr_;                               \
        st16[U][0][tid] = to_bf16u(wg_);                                       \
        st16[U][1][tid] = to_bf16u(wg_ * vr_);                                 \
        st16[U][2][tid] = to_bf16u(wg_ * vr_ * vr_);                           \
        st16[U][3][tid] = to_bf16u(wg_ * vp_);                                 \
        st16[U][4][tid] = to_bf16u(wg_ * vp_ * vp_);                           \
        st16[U][5][tid] = to_bf16u(wg_ * (VZ));                                \
        st16[U][6][tid] = to_bf16u(wg_ * (VZ) * (VZ));                         \
        st16[U][8][tid] = b16_;                                                \
    } while (0)

    #define CONSUME(U) do {                                                    \
        _Pragma("unroll")                                                      \
        for (int b = 0; b < 2; ++b) {                                          \
            uint4 Braw = *(const uint4*)pB[U][b];                              \
            uint4 Nraw = *(const uint4*)pN[U][b];                              \
            short8 Bv = __builtin_bit_cast(short8, Braw);                      \
            unsigned dc0 = pksub(Nraw.x, colpk);                               \
            unsigned dc1 = pksub(Nraw.y, colpk);                               \
            unsigned dc2 = pksub(Nraw.z, colpk);                               \
            unsigned dc3 = pksub(Nraw.w, colpk);                               \
            union { unsigned u[4]; short8 v; } A;                              \
            A.u[0]=oh(dc0); A.u[1]=oh(dc1); A.u[2]=oh(dc2); A.u[3]=oh(dc3);    \
            acc[0] = __builtin_amdgcn_mfma_f32_16x16x32_bf16(A.v, Bv, acc[0], 0,0,0); \
            A.u[0]=oh(pksub(dc0,0x00100010u)); A.u[1]=oh(pksub(dc1,0x00100010u)); \
            A.u[2]=oh(pksub(dc2,0x00100010u)); A.u[3]=oh(pksub(dc3,0x00100010u)); \
            acc[1] = __builtin_amdgcn_mfma_f32_16x16x32_bf16(A.v, Bv, acc[1], 0,0,0); \
            A.u[0]=oh(pksub(dc0,0x00200020u)); A.u[1]=oh(pksub(dc1,0x00200020u)); \
            A.u[2]=oh(pksub(dc2,0x00200020u)); A.u[3]=oh(pksub(dc3,0x00200020u)); \
            acc[2] = __builtin_amdgcn_mfma_f32_16x16x32_bf16(A.v, Bv, acc[2], 0,0,0); \
            u16x2 mx = __builtin_elementwise_max(pkmax(Nraw.x, Nraw.y),        \
                                                 pkmax(Nraw.z, Nraw.w));       \
            unsigned mv = __builtin_bit_cast(unsigned, mx);                    \
            unsigned ms = (mv & 0xFFFFu) > (mv >> 16) ? (mv & 0xFFFFu) : (mv >> 16); \
            if (__any((int)(ms >= 48))) {                                      \
                A.u[0]=oh(pksub(dc0,0x00300030u)); A.u[1]=oh(pksub(dc1,0x00300030u)); \
                A.u[2]=oh(pksub(dc2,0x00300030u)); A.u[3]=oh(pksub(dc3,0x00300030u)); \
                acc[3] = __builtin_amdgcn_mfma_f32_16x16x32_bf16(A.v, Bv, acc[3], 0,0,0); \
            }                                                                  \
        }                                                                      \
    } while (0)

    // component extraction from quad-packed float4s (element K of the quad)
    #define PX(K) ((K)==0 ? c_p0.x : (K)==1 ? c_p0.w : (K)==2 ? c_p1.z : c_p2.y)
    #define PY(K) ((K)==0 ? c_p0.y : (K)==1 ? c_p1.x : (K)==2 ? c_p1.w : c_p2.z)
    #define VXc(K) ((K)==0 ? c_v0.x : (K)==1 ? c_v0.w : (K)==2 ? c_v1.z : c_v2.y)
    #define VYc(K) ((K)==0 ? c_v0.y : (K)==1 ? c_v1.x : (K)==2 ? c_v1.w : c_v2.z)
    #define VZc(K) ((K)==0 ? c_v0.z : (K)==1 ? c_v1.y : (K)==2 ? c_v2.x : c_v2.w)
    #define MMc(K) ((K)==0 ? c_m.x  : (K)==1 ? c_m.y  : (K)==2 ? c_m.z  : c_m.w)

    // ---------- prologue: load iter 0, stage step 0 ----------
    int q0 = gtid;                       // always < nquads (grid << nquads)
    float4 c_p0 = pos4[3*q0+0], c_p1 = pos4[3*q0+1], c_p2 = pos4[3*q0+2];
    float4 c_v0 = vel4[3*q0+0], c_v1 = vel4[3*q0+1], c_v2 = vel4[3*q0+2];
    float4 c_m  = mass4[q0];
    bool cvalid = true;

    STAGE(0, PX(0), PY(0), VXc(0), VYc(0), VZc(0), MMc(0), cvalid);

    for (int it = 0; it < niter; ++it) {
        // prefetch next iteration's quad (clamped; validity masked at stage)
        int qn_raw = (it + 1) * stride + gtid;
        bool nvalid = qn_raw < nquads;
        int qn = nvalid ? qn_raw : (nquads - 1);
        float4 n_p0 = pos4[3*qn+0], n_p1 = pos4[3*qn+1], n_p2 = pos4[3*qn+2];
        float4 n_v0 = vel4[3*qn+0], n_v1 = vel4[3*qn+1], n_v2 = vel4[3*qn+2];
        float4 n_m  = mass4[qn];

        // k = 0: consume buf0, stage k=1 -> buf1
        CONSUME(0);
        STAGE(1, PX(1), PY(1), VXc(1), VYc(1), VZc(1), MMc(1), cvalid);
        // k = 1
        CONSUME(1);
        STAGE(0, PX(2), PY(2), VXc(2), VYc(2), VZc(2), MMc(2), cvalid);
        // k = 2
        CONSUME(0);
        STAGE(1, PX(3), PY(3), VXc(3), VYc(3), VZc(3), MMc(3), cvalid);
        // k = 3: consume, swap prefetched regs in, stage next iter's k=0
        CONSUME(1);
        c_p0 = n_p0; c_p1 = n_p1; c_p2 = n_p2;
        c_v0 = n_v0; c_v1 = n_v1; c_v2 = n_v2;
        c_m  = n_m;  cvalid = nvalid;
        STAGE(0, PX(0), PY(0), VXc(0), VYc(0), VZc(0), MMc(0), cvalid);
    }

    // ---- per-wave D tiles -> LDS (A used 2.0, so scale by 0.5) ----
    if (col < NFEAT) {
        #pragma unroll
        for (int t = 0; t < 4; ++t) {
            #pragma unroll
            for (int r = 0; r < 4; ++r) {
                int bin = 16*t + 4*g + r;    // D: col=lane&15, row=(lane>>4)*4+r
                if (bin < R_BINS)
                    mg[w][bin * NFEAT + col] = acc[t][r] * 0.5f;
            }
        }
    }
    __syncthreads();

    for (int i = tid; i < HSZ; i += blockDim.x) {
        float s = mg[0][i] + mg[1][i] + mg[2][i] + mg[3][i];
        atomicAdd(ghist + i, s);
    }

    // ---- exact scalar tail (n % 4), block 0 ----
    if (blockIdx.x == 0 && tid < (n & 3)) {
        int p = ((n >> 2) << 2) + tid;
        float x = pos[3*p], y = pos[3*p + 1];
        float r = sqrtf(x*x + y*y);
        int bin = (int)floorf(r * 5.0f);
        if (bin >= 0 && bin < R_BINS && r > 0.0f) {
            float invr = 1.0f / r;
            float vxs = vel[3*p], vys = vel[3*p+1], vzs = vel[3*p+2];
            float vr = (x*vxs + y*vys) * invr;
            float vp = (y*vxs - x*vys) * invr;
            float wg = mass[p];
            float* bptr = ghist + bin * NFEAT;
            atomicAdd(bptr + 0, wg);
            atomicAdd(bptr + 1, wg * vr);
            atomicAdd(bptr + 2, wg * vr * vr);
            atomicAdd(bptr + 3, wg * vp);
            atomicAdd(bptr + 4, wg * vp * vp);
            atomicAdd(bptr + 5, wg * vzs);
            atomicAdd(bptr + 6, wg * vzs * vzs);
        }
    }
}

__global__ void disk_finalize_kernel(const float* __restrict__ gh,
                                     float* __restrict__ out)
{
    int b = threadIdx.x;
    if (b >= R_BINS) return;
    const float* s = gh + b * NFEAT;
    float inv  = 1.0f / s[0];
    float vr_m = s[1] * inv, vr2 = s[2] * inv;
    float vp_m = s[3] * inv, vp2 = s[4] * inv;
    float vz_m = s[5] * inv, vz2 = s[6] * inv;
    out[0 * R_BINS + b] = vp_m;
    out[1 * R_BINS + b] = sqrtf(vp2 - vp_m * vp_m);
    out[2 * R_BINS + b] = vr_m;
    out[3 * R_BINS + b] = sqrtf(vr2 - vr_m * vr_m);
    out[4 * R_BINS + b] = vz_m;
    out[5 * R_BINS + b] = sqrtf(vz2 - vz_m * vz_m);
}

extern "C" void kernel_launch(void* const* d_in, const int* in_sizes, int n_in,
                              void* d_out, int out_size, void* d_ws, size_t ws_size,
                              hipStream_t stream)
{
    const float* pos  = (const float*)d_in[0];
    const float* vel  = (const float*)d_in[1];
    const float* mass = (const float*)d_in[2];
    float* out   = (float*)d_out;
    float* ghist = (float*)d_ws;
    int n = in_sizes[2];   // masses: one per particle

    hipMemsetAsync(ghist, 0, HSZ * sizeof(float), stream);

    // 6 blocks/CU (LDS: 24.3 KB/block), even across 8 XCDs
    disk_hist_kernel<<<1536, 256, 0, stream>>>(pos, vel, mass, ghist, n);
    disk_finalize_kernel<<<1, 64, 0, stream>>>(ghist, out);
}

// Round 9
// 138.689 us; speedup vs baseline: 1.0535x; 1.0506x over previous
//
#include <hip/hip_runtime.h>

#define R_BINS 50
#define NFEAT 7
#define HSZ (R_BINS * NFEAT)   // 350
#define STW 264                // u16 per row; 528B stride -> rows on distinct banks

typedef __attribute__((ext_vector_type(8))) short short8;   // 8 bf16
typedef __attribute__((ext_vector_type(4))) float f32x4;
typedef unsigned short u16x2 __attribute__((ext_vector_type(2)));

__device__ __forceinline__ unsigned pksub(unsigned a, unsigned b) {
    u16x2 r = __builtin_bit_cast(u16x2, a) - __builtin_bit_cast(u16x2, b);
    return __builtin_bit_cast(unsigned, r);
}
// packed one-hot: halfword -> bf16 2.0 iff zero (3 ops: pk_min, xor, shl)
__device__ __forceinline__ unsigned oh(unsigned d) {
    u16x2 dd = __builtin_bit_cast(u16x2, d);
    u16x2 one = {1, 1};
    u16x2 m = __builtin_elementwise_min(dd, one);
    return ((__builtin_bit_cast(unsigned, m)) ^ 0x00010001u) << 14;  // 0x4000=bf16 2.0
}

struct Quad { float4 p0, p1, p2, v0, v1, v2, m; };

__global__ __launch_bounds__(256, 4) void disk_hist_kernel(
    const float* __restrict__ pos,
    const float* __restrict__ vel,
    const float* __restrict__ mass,
    float* __restrict__ ghist,
    int n)
{
    // ping-pong staging: rows 0..6 bf16 feats, row 7 zeros, row 8 bins u16
    __shared__ __align__(16) unsigned short st16[2][9][STW];
    __shared__ float mg[4][HSZ];

    const int tid  = threadIdx.x;
    const int lane = tid & 63;
    const int w    = tid >> 6;
    const int col  = lane & 15;
    const int g    = lane >> 4;

    for (int i = tid; i < STW; i += 256) { st16[0][7][i] = 0; st16[1][7][i] = 0; }
    __syncthreads();

    f32x4 acc[4] = {{0,0,0,0},{0,0,0,0},{0,0,0,0},{0,0,0,0}};

    const int brow = (col < NFEAT) ? col : 7;
    const int co   = (w << 6) + (g << 3);
    const unsigned short* pB0 = &st16[0][brow][co];
    const unsigned short* pB1 = &st16[1][brow][co];
    const unsigned short* pN0 = &st16[0][8][co];
    const unsigned short* pN1 = &st16[1][8][co];
    const unsigned cpk0 = (unsigned)col * 0x00010001u;
    const unsigned cpk1 = cpk0 + 0x00100010u;
    const unsigned cpk2 = cpk0 + 0x00200020u;
    const unsigned cpk3 = cpk0 + 0x00300030u;

    const int stride = gridDim.x * blockDim.x;    // 524288
    const int gtid   = blockIdx.x * blockDim.x + tid;
    const int nquads = n >> 2;
    const int niter  = (nquads + stride - 1) / stride;

    const float4* pos4  = (const float4*)pos;
    const float4* vel4  = (const float4*)vel;
    const float4* mass4 = (const float4*)mass;

    #define LOADQ(DST, Q) do {                                                 \
        (DST).p0 = pos4[3*(Q)+0]; (DST).p1 = pos4[3*(Q)+1];                    \
        (DST).p2 = pos4[3*(Q)+2];                                              \
        (DST).v0 = vel4[3*(Q)+0]; (DST).v1 = vel4[3*(Q)+1];                    \
        (DST).v2 = vel4[3*(Q)+2]; (DST).m = mass4[(Q)];                        \
    } while (0)

    // lean producer: rsq only, truncated bf16 (1 shr each), min-clamped bin
    #define STAGE(U, X, Y, VX, VY, VZ, M, VALID) do {                          \
        float x_=(X), y_=(Y), vx_=(VX), vy_=(VY), vz_=(VZ);                    \
        float d_  = x_*x_ + y_*y_;                                             \
        float ir_ = __builtin_amdgcn_rsqf(d_);                                 \
        float r5_ = d_ * ir_ * 5.0f;            /* = r/DR */                   \
        unsigned bu_ = (unsigned)r5_;                                          \
        bu_ = bu_ < 63u ? bu_ : 63u;            /* rows 50..63 discarded */    \
        float wg_ = (VALID) ? (M) : 0.0f;                                      \
        float vr_ = (x_*vx_ + y_*vy_) * ir_;                                   \
        float vp_ = (y_*vx_ - x_*vy_) * ir_;                                   \
        float f1_ = wg_*vr_, f2_ = f1_*vr_;                                    \
        float f3_ = wg_*vp_, f4_ = f3_*vp_;                                    \
        float f5_ = wg_*vz_, f6_ = f5_*vz_;                                    \
        unsigned short* sb_ = &st16[U][0][tid];                                \
        sb_[0*STW] = (unsigned short)(__builtin_bit_cast(unsigned, wg_) >> 16);\
        sb_[1*STW] = (unsigned short)(__builtin_bit_cast(unsigned, f1_) >> 16);\
        sb_[2*STW] = (unsigned short)(__builtin_bit_cast(unsigned, f2_) >> 16);\
        sb_[3*STW] = (unsigned short)(__builtin_bit_cast(unsigned, f3_) >> 16);\
        sb_[4*STW] = (unsigned short)(__builtin_bit_cast(unsigned, f4_) >> 16);\
        sb_[5*STW] = (unsigned short)(__builtin_bit_cast(unsigned, f5_) >> 16);\
        sb_[6*STW] = (unsigned short)(__builtin_bit_cast(unsigned, f6_) >> 16);\
        sb_[8*STW] = (unsigned short)bu_;                                      \
    } while (0)

    #define BATCH(PB, PN) do {                                                 \
        uint4 Braw = *(const uint4*)(PB);                                      \
        uint4 Nraw = *(const uint4*)(PN);                                      \
        short8 Bv = __builtin_bit_cast(short8, Braw);                          \
        union { unsigned u[4]; short8 v; } A;                                  \
        A.u[0]=oh(pksub(Nraw.x,cpk0)); A.u[1]=oh(pksub(Nraw.y,cpk0));          \
        A.u[2]=oh(pksub(Nraw.z,cpk0)); A.u[3]=oh(pksub(Nraw.w,cpk0));          \
        acc[0] = __builtin_amdgcn_mfma_f32_16x16x32_bf16(A.v, Bv, acc[0],0,0,0);\
        A.u[0]=oh(pksub(Nraw.x,cpk1)); A.u[1]=oh(pksub(Nraw.y,cpk1));          \
        A.u[2]=oh(pksub(Nraw.z,cpk1)); A.u[3]=oh(pksub(Nraw.w,cpk1));          \
        acc[1] = __builtin_amdgcn_mfma_f32_16x16x32_bf16(A.v, Bv, acc[1],0,0,0);\
        A.u[0]=oh(pksub(Nraw.x,cpk2)); A.u[1]=oh(pksub(Nraw.y,cpk2));          \
        A.u[2]=oh(pksub(Nraw.z,cpk2)); A.u[3]=oh(pksub(Nraw.w,cpk2));          \
        acc[2] = __builtin_amdgcn_mfma_f32_16x16x32_bf16(A.v, Bv, acc[2],0,0,0);\
        A.u[0]=oh(pksub(Nraw.x,cpk3)); A.u[1]=oh(pksub(Nraw.y,cpk3));          \
        A.u[2]=oh(pksub(Nraw.z,cpk3)); A.u[3]=oh(pksub(Nraw.w,cpk3));          \
        acc[3] = __builtin_amdgcn_mfma_f32_16x16x32_bf16(A.v, Bv, acc[3],0,0,0);\
    } while (0)

    #define CONSUME0() do { BATCH(pB0, pN0); BATCH(pB0+32, pN0+32); } while (0)
    #define CONSUME1() do { BATCH(pB1, pN1); BATCH(pB1+32, pN1+32); } while (0)

    // ---------- prologue ----------
    Quad c, nx;
    LOADQ(c, gtid);                 // gtid < nquads always (stride >> blocks)
    bool cvalid = true;
    STAGE(0, c.p0.x, c.p0.y, c.v0.x, c.v0.y, c.v0.z, c.m.x, cvalid);

    for (int it = 0; it < niter; ++it) {
        int qn_raw = (it + 1) * stride + gtid;
        bool nvalid = qn_raw < nquads;
        int qn = nvalid ? qn_raw : (nquads - 1);
        LOADQ(nx, qn);
        __builtin_amdgcn_sched_barrier(0);   // pin prefetch issue here

        STAGE(1, c.p0.w, c.p1.x, c.v0.w, c.v1.x, c.v1.y, c.m.y, cvalid);
        CONSUME0();                          // staged one full phase ago
        STAGE(0, c.p1.z, c.p1.w, c.v1.z, c.v1.w, c.v2.x, c.m.z, cvalid);
        CONSUME1();
        STAGE(1, c.p2.y, c.p2.z, c.v2.y, c.v2.z, c.v2.w, c.m.w, cvalid);
        CONSUME0();
        c = nx; cvalid = nvalid;
        STAGE(0, c.p0.x, c.p0.y, c.v0.x, c.v0.y, c.v0.z, c.m.x, cvalid);
        CONSUME1();
    }

    // ---- per-wave D tiles -> LDS (A used 2.0 -> scale 0.5) ----
    if (col < NFEAT) {
        #pragma unroll
        for (int t = 0; t < 4; ++t) {
            #pragma unroll
            for (int r = 0; r < 4; ++r) {
                int bin = 16*t + 4*g + r;    // D: col=lane&15, row=(lane>>4)*4+r
                if (bin < R_BINS)
                    mg[w][bin * NFEAT + col] = acc[t][r] * 0.5f;
            }
        }
    }
    __syncthreads();

    for (int i = tid; i < HSZ; i += blockDim.x) {
        float s = mg[0][i] + mg[1][i] + mg[2][i] + mg[3][i];
        atomicAdd(ghist + i, s);
    }

    // ---- exact scalar tail (n % 4), block 0 ----
    if (blockIdx.x == 0 && tid < (n & 3)) {
        int p = ((n >> 2) << 2) + tid;
        float x = pos[3*p], y = pos[3*p + 1];
        float r = sqrtf(x*x + y*y);
        int bin = (int)floorf(r * 5.0f);
        if (bin >= 0 && bin < R_BINS && r > 0.0f) {
            float invr = 1.0f / r;
            float vxs = vel[3*p], vys = vel[3*p+1], vzs = vel[3*p+2];
            float vr = (x*vxs + y*vys) * invr;
            float vp = (y*vxs - x*vys) * invr;
            float wg = mass[p];
            float* bptr = ghist + bin * NFEAT;
            atomicAdd(bptr + 0, wg);
            atomicAdd(bptr + 1, wg * vr);
            atomicAdd(bptr + 2, wg * vr * vr);
            atomicAdd(bptr + 3, wg * vp);
            atomicAdd(bptr + 4, wg * vp * vp);
            atomicAdd(bptr + 5, wg * vzs);
            atomicAdd(bptr + 6, wg * vzs * vzs);
        }
    }
}

__global__ void disk_finalize_kernel(const float* __restrict__ gh,
                                     float* __restrict__ out)
{
    int b = threadIdx.x;
    if (b >= R_BINS) return;
    const float* s = gh + b * NFEAT;
    float inv  = 1.0f / s[0];
    float vr_m = s[1] * inv, vr2 = s[2] * inv;
    float vp_m = s[3] * inv, vp2 = s[4] * inv;
    float vz_m = s[5] * inv, vz2 = s[6] * inv;
    out[0 * R_BINS + b] = vp_m;
    out[1 * R_BINS + b] = sqrtf(vp2 - vp_m * vp_m);
    out[2 * R_BINS + b] = vr_m;
    out[3 * R_BINS + b] = sqrtf(vr2 - vr_m * vr_m);
    out[4 * R_BINS + b] = vz_m;
    out[5 * R_BINS + b] = sqrtf(vz2 - vz_m * vz_m);
}

extern "C" void kernel_launch(void* const* d_in, const int* in_sizes, int n_in,
                              void* d_out, int out_size, void* d_ws, size_t ws_size,
                              hipStream_t stream)
{
    const float* pos  = (const float*)d_in[0];
    const float* vel  = (const float*)d_in[1];
    const float* mass = (const float*)d_in[2];
    float* out   = (float*)d_out;
    float* ghist = (float*)d_ws;
    int n = in_sizes[2];   // masses: one per particle

    hipMemsetAsync(ghist, 0, HSZ * sizeof(float), stream);

    disk_hist_kernel<<<2048, 256, 0, stream>>>(pos, vel, mass, ghist, n);
    disk_finalize_kernel<<<1, 64, 0, stream>>>(ghist, out);
}

// Round 11
// 130.239 us; speedup vs baseline: 1.1218x; 1.0649x over previous
//
#include <hip/hip_runtime.h>

#define R_BINS 50
#define NFEAT 7
#define HSZ (R_BINS * NFEAT)   // 350
#define STW 264                // u16 per row; 528B stride

typedef __attribute__((ext_vector_type(8))) short short8;   // 8 bf16
typedef __attribute__((ext_vector_type(4))) float f32x4;
typedef unsigned short u16x2 __attribute__((ext_vector_type(2)));

__device__ __forceinline__ unsigned pksub(unsigned a, unsigned b) {
    u16x2 r = __builtin_bit_cast(u16x2, a) - __builtin_bit_cast(u16x2, b);
    return __builtin_bit_cast(unsigned, r);
}
// complement one-hot: halfword -> bf16 2.0 iff NOT zero (pk_min + shl = 2 ops)
__device__ __forceinline__ unsigned ohc(unsigned d) {
    u16x2 dd = __builtin_bit_cast(u16x2, d);
    u16x2 one = {1, 1};
    u16x2 m = __builtin_elementwise_min(dd, one);   // 0 iff match else 1
    return __builtin_bit_cast(unsigned, m) << 14;   // 0x4000 = bf16 2.0
}

struct Quad { float4 p0, p1, p2, v0, v1, v2, m; };

__global__ __launch_bounds__(256, 4) void disk_hist_kernel(
    const float* __restrict__ pos,
    const float* __restrict__ vel,
    const float* __restrict__ mass,
    float* __restrict__ ghist,
    int n)
{
    // ping-pong staging: rows 0..6 bf16 feats, row 7 zeros, row 8 bins u16
    __shared__ __align__(16) unsigned short st16[2][9][STW];
    __shared__ float mg[4][HSZ];

    const int tid  = threadIdx.x;
    const int lane = tid & 63;
    const int w    = tid >> 6;
    const int col  = lane & 15;
    const int g    = lane >> 4;

    for (int i = tid; i < STW; i += 256) { st16[0][7][i] = 0; st16[1][7][i] = 0; }
    __syncthreads();

    f32x4 acc[4] = {{0,0,0,0},{0,0,0,0},{0,0,0,0},{0,0,0,0}};
    f32x4 accT   = {0,0,0,0};                       // sum with A = all-2.0

    union { unsigned u[4]; short8 v; } Acst;        // constant all-2.0 A fragment
    Acst.u[0] = Acst.u[1] = Acst.u[2] = Acst.u[3] = 0x40004000u;

    const int brow = (col < NFEAT) ? col : 7;
    const int co   = (w << 6) + (g << 3);
    const unsigned short* pB0 = &st16[0][brow][co];
    const unsigned short* pB1 = &st16[1][brow][co];
    const unsigned short* pN0 = &st16[0][8][co];
    const unsigned short* pN1 = &st16[1][8][co];
    const unsigned cpk0 = (unsigned)col * 0x00010001u;
    const unsigned cpk1 = cpk0 + 0x00100010u;
    const unsigned cpk2 = cpk0 + 0x00200020u;
    const unsigned cpk3 = cpk0 + 0x00300030u;

    const int stride = gridDim.x * blockDim.x;    // 524288
    const int gtid   = blockIdx.x * blockDim.x + tid;
    const int nquads = n >> 2;
    const int niter  = (nquads + stride - 1) / stride;

    const float4* pos4  = (const float4*)pos;
    const float4* vel4  = (const float4*)vel;
    const float4* mass4 = (const float4*)mass;

    #define LOADQ(DST, Q) do {                                                 \
        (DST).p0 = pos4[3*(Q)+0]; (DST).p1 = pos4[3*(Q)+1];                    \
        (DST).p2 = pos4[3*(Q)+2];                                              \
        (DST).v0 = vel4[3*(Q)+0]; (DST).v1 = vel4[3*(Q)+1];                    \
        (DST).v2 = vel4[3*(Q)+2]; (DST).m = mass4[(Q)];                        \
    } while (0)

    // lean producer: guarded rsq, truncated bf16 (1 shr each), no bin clamp
    // (bins 50..127 cancel exactly in the complement merge)
    #define STAGE(U, X, Y, VX, VY, VZ, M, VALID) do {                          \
        float x_=(X), y_=(Y), vx_=(VX), vy_=(VY), vz_=(VZ);                    \
        float d_  = x_*x_ + y_*y_;                                             \
        float ir_ = (d_ > 0.0f) ? __builtin_amdgcn_rsqf(d_) : 0.0f;            \
        float r5_ = d_ * ir_ * 5.0f;            /* = r/DR */                   \
        unsigned bu_ = (unsigned)r5_;                                          \
        float wg_ = (VALID) ? (M) : 0.0f;                                      \
        float vr_ = (x_*vx_ + y_*vy_) * ir_;                                   \
        float vp_ = (y_*vx_ - x_*vy_) * ir_;                                   \
        float f1_ = wg_*vr_, f2_ = f1_*vr_;                                    \
        float f3_ = wg_*vp_, f4_ = f3_*vp_;                                    \
        float f5_ = wg_*vz_, f6_ = f5_*vz_;                                    \
        unsigned short* sb_ = &st16[U][0][tid];                                \
        sb_[0*STW] = (unsigned short)(__builtin_bit_cast(unsigned, wg_) >> 16);\
        sb_[1*STW] = (unsigned short)(__builtin_bit_cast(unsigned, f1_) >> 16);\
        sb_[2*STW] = (unsigned short)(__builtin_bit_cast(unsigned, f2_) >> 16);\
        sb_[3*STW] = (unsigned short)(__builtin_bit_cast(unsigned, f3_) >> 16);\
        sb_[4*STW] = (unsigned short)(__builtin_bit_cast(unsigned, f4_) >> 16);\
        sb_[5*STW] = (unsigned short)(__builtin_bit_cast(unsigned, f5_) >> 16);\
        sb_[6*STW] = (unsigned short)(__builtin_bit_cast(unsigned, f6_) >> 16);\
        sb_[8*STW] = (unsigned short)bu_;                                      \
    } while (0)

    #define BATCH(Braw, Nraw) do {                                             \
        short8 Bv = __builtin_bit_cast(short8, Braw);                          \
        union { unsigned u[4]; short8 v; } A;                                  \
        A.u[0]=ohc(pksub(Nraw.x,cpk0)); A.u[1]=ohc(pksub(Nraw.y,cpk0));        \
        A.u[2]=ohc(pksub(Nraw.z,cpk0)); A.u[3]=ohc(pksub(Nraw.w,cpk0));        \
        acc[0] = __builtin_amdgcn_mfma_f32_16x16x32_bf16(A.v, Bv, acc[0],0,0,0);\
        A.u[0]=ohc(pksub(Nraw.x,cpk1)); A.u[1]=ohc(pksub(Nraw.y,cpk1));        \
        A.u[2]=ohc(pksub(Nraw.z,cpk1)); A.u[3]=ohc(pksub(Nraw.w,cpk1));        \
        acc[1] = __builtin_amdgcn_mfma_f32_16x16x32_bf16(A.v, Bv, acc[1],0,0,0);\
        A.u[0]=ohc(pksub(Nraw.x,cpk2)); A.u[1]=ohc(pksub(Nraw.y,cpk2));        \
        A.u[2]=ohc(pksub(Nraw.z,cpk2)); A.u[3]=ohc(pksub(Nraw.w,cpk2));        \
        acc[2] = __builtin_amdgcn_mfma_f32_16x16x32_bf16(A.v, Bv, acc[2],0,0,0);\
        A.u[0]=ohc(pksub(Nraw.x,cpk3)); A.u[1]=ohc(pksub(Nraw.y,cpk3));        \
        A.u[2]=ohc(pksub(Nraw.z,cpk3)); A.u[3]=ohc(pksub(Nraw.w,cpk3));        \
        acc[3] = __builtin_amdgcn_mfma_f32_16x16x32_bf16(A.v, Bv, acc[3],0,0,0);\
        accT   = __builtin_amdgcn_mfma_f32_16x16x32_bf16(Acst.v, Bv, accT,0,0,0);\
    } while (0)

    #define CONSUME0() do {                                                    \
        uint4 Br0_ = *(const uint4*)pB0;  uint4 Nr0_ = *(const uint4*)pN0;     \
        uint4 Br1_ = *(const uint4*)(pB0+32); uint4 Nr1_ = *(const uint4*)(pN0+32); \
        BATCH(Br0_, Nr0_); BATCH(Br1_, Nr1_);                                  \
    } while (0)
    #define CONSUME1() do {                                                    \
        uint4 Br0_ = *(const uint4*)pB1;  uint4 Nr0_ = *(const uint4*)pN1;     \
        uint4 Br1_ = *(const uint4*)(pB1+32); uint4 Nr1_ = *(const uint4*)(pN1+32); \
        BATCH(Br0_, Nr0_); BATCH(Br1_, Nr1_);                                  \
    } while (0)

    // ---------- prologue ----------
    Quad c, nx;
    LOADQ(c, gtid);                 // gtid < nquads always (stride >> blocks)
    bool cvalid = true;
    STAGE(0, c.p0.x, c.p0.y, c.v0.x, c.v0.y, c.v0.z, c.m.x, cvalid);

    for (int it = 0; it < niter; ++it) {
        int qn_raw = (it + 1) * stride + gtid;
        bool nvalid = qn_raw < nquads;
        int qn = nvalid ? qn_raw : (nquads - 1);
        LOADQ(nx, qn);

        STAGE(1, c.p0.w, c.p1.x, c.v0.w, c.v1.x, c.v1.y, c.m.y, cvalid);
        CONSUME0();                          // staged one full phase ago
        STAGE(0, c.p1.z, c.p1.w, c.v1.z, c.v1.w, c.v2.x, c.m.z, cvalid);
        CONSUME1();
        STAGE(1, c.p2.y, c.p2.z, c.v2.y, c.v2.z, c.v2.w, c.m.w, cvalid);
        CONSUME0();
        c = nx; cvalid = nvalid;
        STAGE(0, c.p0.x, c.p0.y, c.v0.x, c.v0.y, c.v0.z, c.m.x, cvalid);
        CONSUME1();
    }

    // ---- per-wave D tiles -> LDS; hist = (accT - compl)/2 ----
    if (col < NFEAT) {
        #pragma unroll
        for (int t = 0; t < 4; ++t) {
            #pragma unroll
            for (int r = 0; r < 4; ++r) {
                int bin = 16*t + 4*g + r;    // D: col=lane&15, row=(lane>>4)*4+r
                if (bin < R_BINS)
                    mg[w][bin * NFEAT + col] = (accT[r] - acc[t][r]) * 0.5f;
            }
        }
    }
    __syncthreads();

    for (int i = tid; i < HSZ; i += blockDim.x) {
        float s = mg[0][i] + mg[1][i] + mg[2][i] + mg[3][i];
        atomicAdd(ghist + i, s);
    }

    // ---- exact scalar tail (n % 4), block 0 (empty for N=16M) ----
    if (blockIdx.x == 0 && tid < (n & 3)) {
        int p = ((n >> 2) << 2) + tid;
        float x = pos[3*p], y = pos[3*p + 1];
        float r = sqrtf(x*x + y*y);
        int bin = (int)floorf(r * 5.0f);
        if (bin >= 0 && bin < R_BINS && r > 0.0f) {
            float invr = 1.0f / r;
            float vxs = vel[3*p], vys = vel[3*p+1], vzs = vel[3*p+2];
            float vr = (x*vxs + y*vys) * invr;
            float vp = (y*vxs - x*vys) * invr;
            float wg = mass[p];
            float* bptr = ghist + bin * NFEAT;
            atomicAdd(bptr + 0, wg);
            atomicAdd(bptr + 1, wg * vr);
            atomicAdd(bptr + 2, wg * vr * vr);
            atomicAdd(bptr + 3, wg * vp);
            atomicAdd(bptr + 4, wg * vp * vp);
            atomicAdd(bptr + 5, wg * vzs);
            atomicAdd(bptr + 6, wg * vzs * vzs);
        }
    }
}

__global__ void disk_finalize_kernel(const float* __restrict__ gh,
                                     float* __restrict__ out)
{
    int b = threadIdx.x;
    if (b >= R_BINS) return;
    const float* s = gh + b * NFEAT;
    float inv  = 1.0f / s[0];
    float vr_m = s[1] * inv, vr2 = s[2] * inv;
    float vp_m = s[3] * inv, vp2 = s[4] * inv;
    float vz_m = s[5] * inv, vz2 = s[6] * inv;
    out[0 * R_BINS + b] = vp_m;
    out[1 * R_BINS + b] = sqrtf(vp2 - vp_m * vp_m);
    out[2 * R_BINS + b] = vr_m;
    out[3 * R_BINS + b] = sqrtf(vr2 - vr_m * vr_m);
    out[4 * R_BINS + b] = vz_m;
    out[5 * R_BINS + b] = sqrtf(vz2 - vz_m * vz_m);
}

extern "C" void kernel_launch(void* const* d_in, const int* in_sizes, int n_in,
                              void* d_out, int out_size, void* d_ws, size_t ws_size,
                              hipStream_t stream)
{
    const float* pos  = (const float*)d_in[0];
    const float* vel  = (const float*)d_in[1];
    const float* mass = (const float*)d_in[2];
    float* out   = (float*)d_out;
    float* ghist = (float*)d_ws;
    int n = in_sizes[2];   // masses: one per particle

    hipMemsetAsync(ghist, 0, HSZ * sizeof(float), stream);

    disk_hist_kernel<<<2048, 256, 0, stream>>>(pos, vel, mass, ghist, n);
    disk_finalize_kernel<<<1, 64, 0, stream>>>(ghist, out);
}

// Round 12
// 104.940 us; speedup vs baseline: 1.3923x; 1.2411x over previous
//
#include <hip/hip_runtime.h>

#define R_BINS 50
#define NFEAT 7
#define HSZ (R_BINS * NFEAT)   // 350
#define STW 264                // u16 per row; 528B stride

typedef __attribute__((ext_vector_type(8))) short short8;   // 8 bf16
typedef __attribute__((ext_vector_type(4))) float f32x4;

// Forced VOP3P packed ops: value-in/value-out asm, no memory semantics.
__device__ __forceinline__ unsigned pksub(unsigned a, unsigned b) {
    unsigned d;
    asm("v_pk_sub_u16 %0, %1, %2" : "=v"(d) : "v"(a), "v"(b));
    return d;
}
// complement one-hot: halfword -> bf16 2.0 iff NOT zero
__device__ __forceinline__ unsigned ohc(unsigned d, unsigned onepk) {
    unsigned m;
    asm("v_pk_min_u16 %0, %1, %2" : "=v"(m) : "v"(d), "v"(onepk));
    return m << 14;   // 0x4000 = bf16 2.0 where no match
}

struct Quad { float4 p0, p1, p2, v0, v1, v2, m; };

__global__ __launch_bounds__(256, 4) void disk_hist_kernel(
    const float* __restrict__ pos,
    const float* __restrict__ vel,
    const float* __restrict__ mass,
    float* __restrict__ ghist,
    int n)
{
    // ping-pong staging: rows 0..6 bf16 feats, row 7 zeros, row 8 bins u16
    __shared__ __align__(16) unsigned short st16[2][9][STW];
    __shared__ float mg[4][HSZ];

    const int tid  = threadIdx.x;
    const int lane = tid & 63;
    const int w    = tid >> 6;
    const int col  = lane & 15;
    const int g    = lane >> 4;

    for (int i = tid; i < STW; i += 256) { st16[0][7][i] = 0; st16[1][7][i] = 0; }
    __syncthreads();

    f32x4 acc[4] = {{0,0,0,0},{0,0,0,0},{0,0,0,0},{0,0,0,0}};
    f32x4 accT   = {0,0,0,0};                       // sum with A = all-2.0

    union { unsigned u[4]; short8 v; } Acst;        // constant all-2.0 A fragment
    Acst.u[0] = Acst.u[1] = Acst.u[2] = Acst.u[3] = 0x40004000u;

    unsigned onepk = 0x00010001u;
    asm("" : "+v"(onepk));                          // keep in VGPR

    const int brow = (col < NFEAT) ? col : 7;
    const int co   = (w << 6) + (g << 3);
    const unsigned short* pB0 = &st16[0][brow][co];
    const unsigned short* pB1 = &st16[1][brow][co];
    const unsigned short* pN0 = &st16[0][8][co];
    const unsigned short* pN1 = &st16[1][8][co];
    const unsigned cpk0 = (unsigned)col * 0x00010001u;
    const unsigned cpk1 = cpk0 + 0x00100010u;
    const unsigned cpk2 = cpk0 + 0x00200020u;
    const unsigned cpk3 = cpk0 + 0x00300030u;

    const int stride = gridDim.x * blockDim.x;    // 524288
    const int gtid   = blockIdx.x * blockDim.x + tid;
    const int nquads = n >> 2;
    const int niter  = (nquads + stride - 1) / stride;

    const float4* pos4  = (const float4*)pos;
    const float4* vel4  = (const float4*)vel;
    const float4* mass4 = (const float4*)mass;

    #define LOADQ(DST, Q) do {                                                 \
        (DST).p0 = pos4[3*(Q)+0]; (DST).p1 = pos4[3*(Q)+1];                    \
        (DST).p2 = pos4[3*(Q)+2];                                              \
        (DST).v0 = vel4[3*(Q)+0]; (DST).v1 = vel4[3*(Q)+1];                    \
        (DST).v2 = vel4[3*(Q)+2]; (DST).m = mass4[(Q)];                        \
    } while (0)

    // lean producer: guarded rsq, truncated bf16 (1 shr each), no bin clamp
    // (bins 50..127 cancel exactly in the complement merge)
    #define STAGE(U, X, Y, VX, VY, VZ, M, VALID) do {                          \
        float x_=(X), y_=(Y), vx_=(VX), vy_=(VY), vz_=(VZ);                    \
        float d_  = x_*x_ + y_*y_;                                             \
        float ir_ = (d_ > 0.0f) ? __builtin_amdgcn_rsqf(d_) : 0.0f;            \
        float r5_ = d_ * ir_ * 5.0f;            /* = r/DR */                   \
        unsigned bu_ = (unsigned)r5_;                                          \
        float wg_ = (VALID) ? (M) : 0.0f;                                      \
        float vr_ = (x_*vx_ + y_*vy_) * ir_;                                   \
        float vp_ = (y_*vx_ - x_*vy_) * ir_;                                   \
        float f1_ = wg_*vr_, f2_ = f1_*vr_;                                    \
        float f3_ = wg_*vp_, f4_ = f3_*vp_;                                    \
        float f5_ = wg_*vz_, f6_ = f5_*vz_;                                    \
        unsigned short* sb_ = &st16[U][0][tid];                                \
        sb_[0*STW] = (unsigned short)(__builtin_bit_cast(unsigned, wg_) >> 16);\
        sb_[1*STW] = (unsigned short)(__builtin_bit_cast(unsigned, f1_) >> 16);\
        sb_[2*STW] = (unsigned short)(__builtin_bit_cast(unsigned, f2_) >> 16);\
        sb_[3*STW] = (unsigned short)(__builtin_bit_cast(unsigned, f3_) >> 16);\
        sb_[4*STW] = (unsigned short)(__builtin_bit_cast(unsigned, f4_) >> 16);\
        sb_[5*STW] = (unsigned short)(__builtin_bit_cast(unsigned, f5_) >> 16);\
        sb_[6*STW] = (unsigned short)(__builtin_bit_cast(unsigned, f6_) >> 16);\
        sb_[8*STW] = (unsigned short)bu_;                                      \
    } while (0)

    #define BATCH(Braw, Nraw) do {                                             \
        short8 Bv = __builtin_bit_cast(short8, Braw);                          \
        union { unsigned u[4]; short8 v; } A;                                  \
        A.u[0]=ohc(pksub(Nraw.x,cpk0),onepk); A.u[1]=ohc(pksub(Nraw.y,cpk0),onepk); \
        A.u[2]=ohc(pksub(Nraw.z,cpk0),onepk); A.u[3]=ohc(pksub(Nraw.w,cpk0),onepk); \
        acc[0] = __builtin_amdgcn_mfma_f32_16x16x32_bf16(A.v, Bv, acc[0],0,0,0);\
        A.u[0]=ohc(pksub(Nraw.x,cpk1),onepk); A.u[1]=ohc(pksub(Nraw.y,cpk1),onepk); \
        A.u[2]=ohc(pksub(Nraw.z,cpk1),onepk); A.u[3]=ohc(pksub(Nraw.w,cpk1),onepk); \
        acc[1] = __builtin_amdgcn_mfma_f32_16x16x32_bf16(A.v, Bv, acc[1],0,0,0);\
        A.u[0]=ohc(pksub(Nraw.x,cpk2),onepk); A.u[1]=ohc(pksub(Nraw.y,cpk2),onepk); \
        A.u[2]=ohc(pksub(Nraw.z,cpk2),onepk); A.u[3]=ohc(pksub(Nraw.w,cpk2),onepk); \
        acc[2] = __builtin_amdgcn_mfma_f32_16x16x32_bf16(A.v, Bv, acc[2],0,0,0);\
        A.u[0]=ohc(pksub(Nraw.x,cpk3),onepk); A.u[1]=ohc(pksub(Nraw.y,cpk3),onepk); \
        A.u[2]=ohc(pksub(Nraw.z,cpk3),onepk); A.u[3]=ohc(pksub(Nraw.w,cpk3),onepk); \
        acc[3] = __builtin_amdgcn_mfma_f32_16x16x32_bf16(A.v, Bv, acc[3],0,0,0);\
        accT   = __builtin_amdgcn_mfma_f32_16x16x32_bf16(Acst.v, Bv, accT,0,0,0);\
    } while (0)

    #define CONSUME0() do {                                                    \
        uint4 Br0_ = *(const uint4*)pB0;  uint4 Nr0_ = *(const uint4*)pN0;     \
        uint4 Br1_ = *(const uint4*)(pB0+32); uint4 Nr1_ = *(const uint4*)(pN0+32); \
        BATCH(Br0_, Nr0_); BATCH(Br1_, Nr1_);                                  \
    } while (0)
    #define CONSUME1() do {                                                    \
        uint4 Br0_ = *(const uint4*)pB1;  uint4 Nr0_ = *(const uint4*)pN1;     \
        uint4 Br1_ = *(const uint4*)(pB1+32); uint4 Nr1_ = *(const uint4*)(pN1+32); \
        BATCH(Br0_, Nr0_); BATCH(Br1_, Nr1_);                                  \
    } while (0)

    // ---------- prologue ----------
    Quad c, nx;
    LOADQ(c, gtid);                 // gtid < nquads always (stride >> blocks)
    bool cvalid = true;
    STAGE(0, c.p0.x, c.p0.y, c.v0.x, c.v0.y, c.v0.z, c.m.x, cvalid);

    for (int it = 0; it < niter; ++it) {
        int qn_raw = (it + 1) * stride + gtid;
        bool nvalid = qn_raw < nquads;
        int qn = nvalid ? qn_raw : (nquads - 1);
        LOADQ(nx, qn);

        STAGE(1, c.p0.w, c.p1.x, c.v0.w, c.v1.x, c.v1.y, c.m.y, cvalid);
        CONSUME0();                          // staged one full phase ago
        STAGE(0, c.p1.z, c.p1.w, c.v1.z, c.v1.w, c.v2.x, c.m.z, cvalid);
        CONSUME1();
        STAGE(1, c.p2.y, c.p2.z, c.v2.y, c.v2.z, c.v2.w, c.m.w, cvalid);
        CONSUME0();
        c = nx; cvalid = nvalid;
        STAGE(0, c.p0.x, c.p0.y, c.v0.x, c.v0.y, c.v0.z, c.m.x, cvalid);
        CONSUME1();
    }

    // ---- per-wave D tiles -> LDS; hist = (accT - compl)/2 ----
    if (col < NFEAT) {
        #pragma unroll
        for (int t = 0; t < 4; ++t) {
            #pragma unroll
            for (int r = 0; r < 4; ++r) {
                int bin = 16*t + 4*g + r;    // D: col=lane&15, row=(lane>>4)*4+r
                if (bin < R_BINS)
                    mg[w][bin * NFEAT + col] = (accT[r] - acc[t][r]) * 0.5f;
            }
        }
    }
    __syncthreads();

    for (int i = tid; i < HSZ; i += blockDim.x) {
        float s = mg[0][i] + mg[1][i] + mg[2][i] + mg[3][i];
        atomicAdd(ghist + i, s);
    }

    // ---- exact scalar tail (n % 4), block 0 (empty for N=16M) ----
    if (blockIdx.x == 0 && tid < (n & 3)) {
        int p = ((n >> 2) << 2) + tid;
        float x = pos[3*p], y = pos[3*p + 1];
        float r = sqrtf(x*x + y*y);
        int bin = (int)floorf(r * 5.0f);
        if (bin >= 0 && bin < R_BINS && r > 0.0f) {
            float invr = 1.0f / r;
            float vxs = vel[3*p], vys = vel[3*p+1], vzs = vel[3*p+2];
            float vr = (x*vxs + y*vys) * invr;
            float vp = (y*vxs - x*vys) * invr;
            float wg = mass[p];
            float* bptr = ghist + bin * NFEAT;
            atomicAdd(bptr + 0, wg);
            atomicAdd(bptr + 1, wg * vr);
            atomicAdd(bptr + 2, wg * vr * vr);
            atomicAdd(bptr + 3, wg * vp);
            atomicAdd(bptr + 4, wg * vp * vp);
            atomicAdd(bptr + 5, wg * vzs);
            atomicAdd(bptr + 6, wg * vzs * vzs);
        }
    }
}

__global__ void disk_finalize_kernel(const float* __restrict__ gh,
                                     float* __restrict__ out)
{
    int b = threadIdx.x;
    if (b >= R_BINS) return;
    const float* s = gh + b * NFEAT;
    float inv  = 1.0f / s[0];
    float vr_m = s[1] * inv, vr2 = s[2] * inv;
    float vp_m = s[3] * inv, vp2 = s[4] * inv;
    float vz_m = s[5] * inv, vz2 = s[6] * inv;
    out[0 * R_BINS + b] = vp_m;
    out[1 * R_BINS + b] = sqrtf(vp2 - vp_m * vp_m);
    out[2 * R_BINS + b] = vr_m;
    out[3 * R_BINS + b] = sqrtf(vr2 - vr_m * vr_m);
    out[4 * R_BINS + b] = vz_m;
    out[5 * R_BINS + b] = sqrtf(vz2 - vz_m * vz_m);
}

extern "C" void kernel_launch(void* const* d_in, const int* in_sizes, int n_in,
                              void* d_out, int out_size, void* d_ws, size_t ws_size,
                              hipStream_t stream)
{
    const float* pos  = (const float*)d_in[0];
    const float* vel  = (const float*)d_in[1];
    const float* mass = (const float*)d_in[2];
    float* out   = (float*)d_out;
    float* ghist = (float*)d_ws;
    int n = in_sizes[2];   // masses: one per particle

    hipMemsetAsync(ghist, 0, HSZ * sizeof(float), stream);

    disk_hist_kernel<<<2048, 256, 0, stream>>>(pos, vel, mass, ghist, n);
    disk_finalize_kernel<<<1, 64, 0, stream>>>(ghist, out);
}